// Round 1
// baseline (249.066 us; speedup 1.0000x reference)
//
#include <hip/hip_runtime.h>
#include <hip/hip_bf16.h>
#include <cstdint>

// Problem: B=256, N0=64, D0=128, N1=64, D1=128 (all fp32 in/out).
// u[b,n1,n0,d1] = sum_d0 x[b,n0,d0]*W[n1,n0,d0,d1]
// s = sum_n0 u ; logit = (u . s)/sqrt(128) ; c = softmax_n1(logit) + bias
// out[b,n1,d1] = sum_n0 u*c
//
// ws layout: u bf16 [B][N1][N0][D1] @0 (268435456 B)
//            logits f32 [B][N1][N0] @268435456 (4194304 B)
//            c      f32 [B][N1][N0] @272629760 (4194304 B)

#define BB 256
#define NN0 64
#define DD0 128
#define NN1 64
#define DD1 128

typedef __attribute__((ext_vector_type(8))) short bf16x8;
typedef __attribute__((ext_vector_type(4))) float f32x4;

__device__ __forceinline__ ushort f2bf(float f) {
  uint32_t b = __float_as_uint(f);
  b += 0x7FFFu + ((b >> 16) & 1u);      // RNE
  return (ushort)(b >> 16);
}
__device__ __forceinline__ float bf2f(ushort h) {
  return __uint_as_float(((uint32_t)h) << 16);
}

// ---------------- K1: u = x @ W  (per (n1,n0): [256x128] = [256x128]x[128x128])
__global__ __launch_bounds__(512) void k1_gemm(
    const float* __restrict__ x, const float* __restrict__ W,
    ushort* __restrict__ u)
{
  __shared__ char lds[49152];           // A: 32768 B (256 rows x 64k bf16), Bt: 16384 B (128 n x 64k)
  char* Alds = lds;
  char* Blds = lds + 32768;

  const int bid = blockIdx.x;
  const int n1 = bid >> 6, n0 = bid & 63;
  const int t = threadIdx.x;
  const int lane = t & 63, wave = t >> 6;
  const int wm = wave >> 1, wn = wave & 1;   // 4 M-waves x 2 N-waves

  const float* xb = x + n0 * DD0;                                  // + b*8192 + d0
  const float* Wb = W + ((size_t)n1 * NN0 + n0) * (DD0 * DD1);     // [d0][d1]
  ushort* ub = u + ((size_t)n1 * 8192 + (size_t)n0 * 128);         // + b*524288 + d1

  f32x4 acc[4][4];
#pragma unroll
  for (int i = 0; i < 4; ++i)
#pragma unroll
    for (int j = 0; j < 4; ++j) acc[i][j] = {0.f, 0.f, 0.f, 0.f};

  for (int khalf = 0; khalf < 2; ++khalf) {
    const int k0 = khalf * 64;
    __syncthreads();
    // stage A (x rows, b-major, k-contiguous, bf16, XOR-swizzled)
#pragma unroll
    for (int i = 0; i < 8; ++i) {
      int c = t + i * 512;              // 4096 float4 chunks: 256 rows x 16
      int row = c >> 4;
      int c4 = c & 15;
      const float4 v = *reinterpret_cast<const float4*>(xb + (size_t)row * 8192 + k0 + c4 * 4);
      ushort4 h;
      h.x = f2bf(v.x); h.y = f2bf(v.y); h.z = f2bf(v.z); h.w = f2bf(v.w);
      int byte = (row * 128 + c4 * 8) ^ ((row & 7) << 4);
      *reinterpret_cast<ushort4*>(Alds + byte) = h;
    }
    // stage Bt = W^T (n-major rows, k-contiguous) via lane-coalesced column gather
#pragma unroll
    for (int i = 0; i < 2; ++i) {
      int c = t + i * 512;              // 1024 chunks: 128 n x 8 k-chunks
      int n = c & 127;
      int kc = c >> 7;                  // 0..7
      ushort hh[8];
#pragma unroll
      for (int j = 0; j < 8; ++j)
        hh[j] = f2bf(Wb[(size_t)(k0 + kc * 8 + j) * 128 + n]);
      uint32_t w0 = (uint32_t)hh[0] | ((uint32_t)hh[1] << 16);
      uint32_t w1 = (uint32_t)hh[2] | ((uint32_t)hh[3] << 16);
      uint32_t w2 = (uint32_t)hh[4] | ((uint32_t)hh[5] << 16);
      uint32_t w3 = (uint32_t)hh[6] | ((uint32_t)hh[7] << 16);
      int byte = (n * 128 + kc * 16) ^ ((n & 7) << 4);
      *reinterpret_cast<uint4*>(Blds + byte) = make_uint4(w0, w1, w2, w3);
    }
    __syncthreads();
    // MFMA over this K-half
#pragma unroll
    for (int kk = 0; kk < 64; kk += 32) {
      const int kb = kk + (lane >> 4) * 8;
      bf16x8 af[4], bfr[4];
#pragma unroll
      for (int mf = 0; mf < 4; ++mf) {
        int row = wm * 64 + mf * 16 + (lane & 15);
        int byte = (row * 128 + kb * 2) ^ ((row & 7) << 4);
        af[mf] = *reinterpret_cast<bf16x8*>(Alds + byte);
      }
#pragma unroll
      for (int nf = 0; nf < 4; ++nf) {
        int n = wn * 64 + nf * 16 + (lane & 15);
        int byte = (n * 128 + kb * 2) ^ ((n & 7) << 4);
        bfr[nf] = *reinterpret_cast<bf16x8*>(Blds + byte);
      }
#pragma unroll
      for (int mf = 0; mf < 4; ++mf)
#pragma unroll
        for (int nf = 0; nf < 4; ++nf)
          acc[mf][nf] = __builtin_amdgcn_mfma_f32_16x16x32_bf16(af[mf], bfr[nf], acc[mf][nf], 0, 0, 0);
    }
  }

  // epilogue: stage C through LDS (rows of 128 d1 bf16 = 256 B) for vector global writes.
  // Two chunks of 128 rows (reuse A region, 32 KB each).
#pragma unroll
  for (int half = 0; half < 2; ++half) {
    __syncthreads();
    if ((wm >> 1) == half) {            // waves holding rows [half*128, half*128+128)
      int wml = wm & 1;
#pragma unroll
      for (int mf = 0; mf < 4; ++mf) {
        int rowb = wml * 64 + mf * 16 + (lane >> 4) * 4;
#pragma unroll
        for (int nf = 0; nf < 4; ++nf) {
          int col = wn * 64 + nf * 16 + (lane & 15);
#pragma unroll
          for (int r = 0; r < 4; ++r) {
            int rr = rowb + r;
            int byte = (rr * 256 + col * 2) ^ ((rr & 7) << 4);
            *reinterpret_cast<ushort*>(lds + byte) = f2bf(acc[mf][nf][r]);
          }
        }
      }
    }
    __syncthreads();
#pragma unroll
    for (int i = 0; i < 4; ++i) {
      int c = t + i * 512;              // 2048 x 16B chunks = 32 KB
      int rowl = c >> 4;
      int cb = (c & 15) * 16;
      int sbyte = (rowl * 256 + cb) ^ ((rowl & 7) << 4);
      uint4 v = *reinterpret_cast<uint4*>(lds + sbyte);
      int row = half * 128 + rowl;      // global b
      *reinterpret_cast<uint4*>(ub + (size_t)row * 524288 + cb / 2) = v;
    }
  }
}

// ---------------- K2: s = sum_n0 u ; logits = (u . s)/sqrt(128)
__global__ __launch_bounds__(256) void k2_logits(
    const ushort* __restrict__ u, float* __restrict__ logits)
{
  const int bid = blockIdx.x;           // b*64 + n1
  const ushort* up = u + (size_t)bid * 8192;   // [n0][d1] 64x128
  const int t = threadIdx.x;

  __shared__ float part[8][128];
  __shared__ float sS[128];
  __shared__ float part2[256];

  {
    int d4 = (t & 31) * 4;
    int g = t >> 5;                     // n0 group of 8
    float4 a = {0, 0, 0, 0};
    for (int n0 = g * 8; n0 < g * 8 + 8; ++n0) {
      ushort4 v = *reinterpret_cast<const ushort4*>(up + n0 * 128 + d4);
      a.x += bf2f(v.x); a.y += bf2f(v.y); a.z += bf2f(v.z); a.w += bf2f(v.w);
    }
    *reinterpret_cast<float4*>(&part[g][d4]) = a;
  }
  __syncthreads();
  if (t < 128) {
    float s = 0;
#pragma unroll
    for (int g = 0; g < 8; ++g) s += part[g][t];
    sS[t] = s;
  }
  __syncthreads();
  {
    int n0 = t >> 2, q = t & 3;
    float acc = 0;
#pragma unroll
    for (int j = 0; j < 32; j += 4) {
      int d = q * 32 + j;
      ushort4 v = *reinterpret_cast<const ushort4*>(up + n0 * 128 + d);
      acc += bf2f(v.x) * sS[d] + bf2f(v.y) * sS[d + 1] + bf2f(v.z) * sS[d + 2] + bf2f(v.w) * sS[d + 3];
    }
    part2[t] = acc;
  }
  __syncthreads();
  if (t < 64) {
    float l = (part2[t * 4] + part2[t * 4 + 1] + part2[t * 4 + 2] + part2[t * 4 + 3]) * 0.08838834764831845f;
    logits[(size_t)bid * 64 + t] = l;
  }
}

// ---------------- K3: softmax over n1 (per (b,n0)) + bias
__global__ __launch_bounds__(64) void k3_softmax(
    const float* __restrict__ logits, const float* __restrict__ bias,
    float* __restrict__ cc)
{
  const int b = blockIdx.x;
  const int t = threadIdx.x;            // = n0
  __shared__ float L[64][64];           // [n1][n0]
  const float* lp = logits + (size_t)b * 4096;
  for (int i = 0; i < 64; ++i) L[i][t] = lp[i * 64 + t];
  __syncthreads();
  float m = -1e30f;
#pragma unroll
  for (int n1 = 0; n1 < 64; ++n1) m = fmaxf(m, L[n1][t]);
  float sum = 0.f;
#pragma unroll
  for (int n1 = 0; n1 < 64; ++n1) {
    float e = __expf(L[n1][t] - m);
    L[n1][t] = e;
    sum += e;
  }
  float inv = 1.0f / sum;
  float* cp = cc + (size_t)b * 4096;
  for (int n1 = 0; n1 < 64; ++n1)
    cp[n1 * 64 + t] = L[n1][t] * inv + bias[n1 * 64 + t];
}

// ---------------- K4: out[b,n1,d1] = sum_n0 u * c
__global__ __launch_bounds__(128) void k4_out(
    const ushort* __restrict__ u, const float* __restrict__ cc,
    float* __restrict__ out)
{
  const int bid = blockIdx.x;           // b*64 + n1
  const ushort* up = u + (size_t)bid * 8192;
  const int t = threadIdx.x;
  __shared__ float cL[64];
  __shared__ float part[4][128];
  if (t < 64) cL[t] = cc[(size_t)bid * 64 + t];
  __syncthreads();
  int d4 = (t & 31) * 4, g = t >> 5;    // g: n0 group of 16
  float4 a = {0, 0, 0, 0};
  for (int n0 = g * 16; n0 < g * 16 + 16; ++n0) {
    ushort4 v = *reinterpret_cast<const ushort4*>(up + n0 * 128 + d4);
    float c = cL[n0];
    a.x += bf2f(v.x) * c; a.y += bf2f(v.y) * c; a.z += bf2f(v.z) * c; a.w += bf2f(v.w) * c;
  }
  *reinterpret_cast<float4*>(&part[g][d4]) = a;
  __syncthreads();
  if (t < 128) {
    float r = part[0][t] + part[1][t] + part[2][t] + part[3][t];
    out[(size_t)bid * 128 + t] = r;
  }
}

extern "C" void kernel_launch(void* const* d_in, const int* in_sizes, int n_in,
                              void* d_out, int out_size, void* d_ws, size_t ws_size,
                              hipStream_t stream) {
  const float* x = (const float*)d_in[0];
  const float* W = (const float*)d_in[1];
  const float* bias = (const float*)d_in[2];
  float* out = (float*)d_out;

  ushort* u = (ushort*)d_ws;                                   // 268435456 B
  float* logits = (float*)((char*)d_ws + 268435456u);          // 4194304 B
  float* cc = (float*)((char*)d_ws + 268435456u + 4194304u);   // 4194304 B
  // requires ws_size >= 276824064; no fallback path (will restructure if ws is smaller)

  hipLaunchKernelGGL(k1_gemm,    dim3(NN1 * NN0), dim3(512), 0, stream, x, W, u);
  hipLaunchKernelGGL(k2_logits,  dim3(BB * NN1),  dim3(256), 0, stream, u, logits);
  hipLaunchKernelGGL(k3_softmax, dim3(BB),        dim3(64),  0, stream, logits, bias, cc);
  hipLaunchKernelGGL(k4_out,     dim3(BB * NN1),  dim3(128), 0, stream, u, cc, out);
}